// Round 8
// baseline (327.404 us; speedup 1.0000x reference)
//
#include <hip/hip_runtime.h>

#define BTOT 32768

using f32x4 = __attribute__((ext_vector_type(4))) float;
using half8 = __attribute__((ext_vector_type(8))) _Float16;

typedef const __attribute__((address_space(1))) unsigned int* gptr_t;
typedef __attribute__((address_space(3))) unsigned int* lptr_t;

__device__ __forceinline__ void gl2lds16(void* lds, const void* g) {
    __builtin_amdgcn_global_load_lds((gptr_t)g, (lptr_t)lds, 16, 0, 0);
}

__device__ __forceinline__ float sigm(float x) {
    return __builtin_amdgcn_rcpf(1.0f + __expf(-x));
}
__device__ __forceinline__ float tanh_(float x) {
    x = fminf(fmaxf(x, -15.0f), 15.0f);
    float e = __expf(2.0f * x);
    return (e - 1.0f) * __builtin_amdgcn_rcpf(e + 1.0f);
}

// ---------------------------------------------------------------------------
// Layouts:
//  W1sw (gemm1 B, LDS path): [2 nb][2 kt][128][64], XOR-swizzled granules.
//  Wlin (lstm B, register path): [4 tile][8 kt][192 rows][64] LINEAR:
//      row*64 + plane*32 + k  (plane 0 = hi, 1 = lo)
//  Xlin/H1lin: [8 kt][nMB][128 rows][64] LINEAR, same row format.
// ---------------------------------------------------------------------------
__global__ __launch_bounds__(256) void pack_kernel(
    const float* __restrict__ W1,
    const float* __restrict__ Wih0, const float* __restrict__ bih0, const float* __restrict__ bhh0,
    const float* __restrict__ Wih1, const float* __restrict__ bih1, const float* __restrict__ bhh1,
    _Float16* __restrict__ W1sw,
    _Float16* __restrict__ W0lin, float* __restrict__ bp0,
    _Float16* __restrict__ W1lin, float* __restrict__ bp1)
{
    int tid = blockIdx.x * 256 + threadIdx.x;
    if (tid < 256 * 64) {
        int n = tid >> 6, k = tid & 63;
        float v = (k < 63) ? 32.0f * W1[n * 63 + k] : 0.0f;
        _Float16 h = (_Float16)v;
        _Float16 l = (_Float16)(v - (float)h);
        int nb = n >> 7, r = n & 127, kt = k >> 5, kk = k & 31;
        size_t bb = (size_t)nb * 16384 + kt * 8192 + r * 64 + (kk & 7);
        W1sw[bb + ((((kk >> 3)) ^ (r & 7)) << 3)] = h;
        W1sw[bb + (((4 + (kk >> 3)) ^ (r & 7)) << 3)] = l;
    }
    int t2 = tid - 256 * 64;
    if (t2 >= 0 && t2 < 2 * 768 * 256) {
        int which = t2 / 196608;
        int rem   = t2 % 196608;
        int rlin = rem >> 8, k = rem & 255;
        int tile = rlin / 192;
        int rr = rlin - tile * 192;
        int g = rr >> 6, jj = rr & 63;
        int orig = ((g == 0) ? 0 : (g == 1) ? 512 : 768) + tile * 64 + jj;
        const float* W = which ? Wih1 : Wih0;
        float v = 32.0f * W[orig * 256 + k];
        _Float16 h = (_Float16)v;
        _Float16 l = (_Float16)(v - (float)h);
        int kt = k >> 5, kk = k & 31;
        _Float16* Wd = which ? W1lin : W0lin;
        size_t bb = (size_t)(tile * 8 + kt) * 12288 + rr * 64;
        Wd[bb + kk] = h;
        Wd[bb + 32 + kk] = l;
        if (k == 0) {
            float bb2 = which ? (bih1[orig] + bhh1[orig]) : (bih0[orig] + bhh0[orig]);
            (which ? bp1 : bp0)[rlin] = bb2;
        }
    }
}

// ---------------------------------------------------------------------------
// GEMM1 with fused feature-prep (LDS path, swizzled — unchanged except the
// output image is now LINEAR). BM=128, BN=128 (grid.y=2), K=64.
// ---------------------------------------------------------------------------
__global__ __launch_bounds__(256) void gemm1_kernel(
    const float* __restrict__ aM, const float* __restrict__ RMB,
    const _Float16* __restrict__ W1sw, const float* __restrict__ b1,
    _Float16* __restrict__ Xlin, int nMB)
{
    __shared__ _Float16 sm[32768];   // A:[2kt][128][64]=16384, B same
    const int t = threadIdx.x;
    const int mb = blockIdx.x, nb = blockIdx.y;
    const int m0 = mb * 128;
    {
        int o = t * 8;
#pragma unroll
        for (int it = 0; it < 8; it++)
            gl2lds16(&sm[16384 + o + it * 2048], &W1sw[(size_t)nb * 16384 + o + it * 2048]);
    }
    if (t < 128) {
        int i = m0 + t;
        const float* ap = aM + (size_t)i * 18;
        const float* rp = RMB + (size_t)i * 54;
        float a[18], R[54];
#pragma unroll
        for (int q = 0; q < 9; q++)  { float2 v = *(const float2*)&ap[q * 2]; a[q*2] = v.x; a[q*2+1] = v.y; }
#pragma unroll
        for (int q = 0; q < 27; q++) { float2 v = *(const float2*)&rp[q * 2]; R[q*2] = v.x; R[q*2+1] = v.y; }
        const float* R6 = R + 45;
        float d[64];
        d[0] = -10.0f * R6[3]; d[1] = -10.0f * R6[4]; d[2] = -10.0f * R6[5];
#pragma unroll
        for (int n = 0; n < 5; n++) {
            float v0 = a[n*3+0] - a[15], v1 = a[n*3+1] - a[16], v2 = a[n*3+2] - a[17];
#pragma unroll
            for (int k = 0; k < 3; k++)
                d[3 + n*3 + k] = v0 * R6[k] + v1 * R6[3 + k] + v2 * R6[6 + k];
        }
#pragma unroll
        for (int n = 0; n < 5; n++)
#pragma unroll
            for (int ii = 0; ii < 3; ii++)
#pragma unroll
                for (int k = 0; k < 3; k++)
                    d[18 + n*9 + ii*3 + k] =
                        R6[ii] * R[n*9 + k] + R6[3 + ii] * R[n*9 + 3 + k] + R6[6 + ii] * R[n*9 + 6 + k];
        d[63] = 0.0f;
        int sx = t & 7;
#pragma unroll
        for (int kt = 0; kt < 2; kt++)
#pragma unroll
            for (int kg = 0; kg < 4; kg++) {
                _Float16 hh[8], ll[8];
#pragma unroll
                for (int e = 0; e < 8; e++) {
                    int di = kt * 32 + kg * 8 + e;
                    float v = (di < 63) ? 16.0f * d[di] : 0.0f;
                    _Float16 h = (_Float16)v;
                    hh[e] = h; ll[e] = (_Float16)(v - (float)h);
                }
                int base = kt * 8192 + t * 64;
                *(half8*)&sm[base + ((kg ^ sx) << 3)]       = *(half8*)hh;
                *(half8*)&sm[base + (((kg + 4) ^ sx) << 3)] = *(half8*)ll;
            }
    }
    asm volatile("s_waitcnt vmcnt(0)" ::: "memory");
    __syncthreads();
    const int lane = t & 63, wid = t >> 6;
    const int wr = wid >> 1, wc = wid & 1;
    const int r16 = lane & 15, g4 = lane >> 4;
    const int sx = r16 & 7;
    const int aghi = (g4 ^ sx) << 3;
    const int aglo = ((g4 + 4) ^ sx) << 3;
    f32x4 acc[4][4] = {};
#pragma unroll
    for (int kt = 0; kt < 2; kt++) {
        half8 ah[4], al[4];
#pragma unroll
        for (int i = 0; i < 4; i++) {
            int ra = kt * 8192 + (wr * 64 + i * 16 + r16) * 64;
            ah[i] = *(const half8*)&sm[ra + aghi];
            al[i] = *(const half8*)&sm[ra + aglo];
        }
#pragma unroll
        for (int j = 0; j < 4; j++) {
            int rb = 16384 + kt * 8192 + (wc * 64 + j * 16 + r16) * 64;
            half8 bh = *(const half8*)&sm[rb + aghi];
            half8 bl = *(const half8*)&sm[rb + aglo];
#pragma unroll
            for (int i = 0; i < 4; i++) {
                acc[i][j] = __builtin_amdgcn_mfma_f32_16x16x32_f16(ah[i], bh, acc[i][j], 0, 0, 0);
                acc[i][j] = __builtin_amdgcn_mfma_f32_16x16x32_f16(ah[i], bl, acc[i][j], 0, 0, 0);
                acc[i][j] = __builtin_amdgcn_mfma_f32_16x16x32_f16(al[i], bh, acc[i][j], 0, 0, 0);
            }
        }
    }
    const float inv = 1.0f / 512.0f;
    __syncthreads();   // sm dead; reuse as output staging [4 kthL][128][64] LINEAR
#pragma unroll
    for (int i = 0; i < 4; i++)
#pragma unroll
        for (int j = 0; j < 4; j++) {
            int col = nb * 128 + wc * 64 + j * 16 + r16;
            float bb = b1[col];
            int kthL = (col >> 5) & 3, kk = col & 31;
#pragma unroll
            for (int rr = 0; rr < 4; rr++) {
                int r = wr * 64 + i * 16 + g4 * 4 + rr;
                float v = fmaxf(acc[i][j][rr] * inv + bb, 0.0f) * 8.0f;
                _Float16 h = (_Float16)v;
                _Float16 l = (_Float16)(v - (float)h);
                int off = kthL * 8192 + r * 64;
                sm[off + kk] = h;
                sm[off + 32 + kk] = l;
            }
        }
    __syncthreads();
#pragma unroll
    for (int c = 0; c < 16; c++)
        *(half8*)&Xlin[((size_t)(nb * 4 + (c >> 2)) * nMB + mb) * 8192 + (c & 3) * 2048 + t * 8] =
            *(half8*)&sm[c * 2048 + t * 8];
}

// ---------------------------------------------------------------------------
// LSTM GEMM — register-resident, ZERO LDS / ZERO barriers in the K-loop.
// 256 threads = 4 waves (2 wr x 2 wu); wave tile 64 rows x 16 cols x 3 gates.
// BM=128, block cols = 32 (tile8 of 8), K=256 in 8 steps. A and B fragments
// loaded global->VGPR with 1-step ping-pong prefetch; compiler emits counted
// vmcnt automatically. ~190 VGPR -> 8 waves/CU, no lockstep.
// OUTF32=0: h1 -> H1lin (LDS-staged coalesced store).
// OUTF32=1: fused head partial (32 cols) -> outP[CB][8][10].
// ---------------------------------------------------------------------------
template<int OUTF32>
__global__ __launch_bounds__(256, 2) void lstm_kernel(
    const _Float16* __restrict__ X, const _Float16* __restrict__ W,
    const float* __restrict__ bp, float inv,
    _Float16* __restrict__ H, const float* __restrict__ W2,
    float* __restrict__ outP, int nMB)
{
    __shared__ _Float16 smh[9216];     // 18 KB: [128][64] stage / fb+W2s
    const int t = threadIdx.x;
    const int nwg = gridDim.x, hb = blockIdx.x;
    const int per = nwg >> 3;
    const int L = (hb & 7) * per + (hb >> 3);   // XCD-grouped: same mb -> same XCD
    const int mb = L >> 3, tile8 = L & 7;
    const int tileW = tile8 >> 1;
    const int m0 = mb * 128;
    const int lane = t & 63, wid = t >> 6;
    const int wr = wid >> 1, wu = wid & 1;
    const int r16 = lane & 15, g4 = lane >> 4;
    const int coll = wu * 16 + r16;             // col within block's 32
    const int bcol = (tile8 & 1) * 32 + coll;   // row-col within W tile of 64

    int aoff[4];
#pragma unroll
    for (int i = 0; i < 4; i++) aoff[i] = (wr * 64 + i * 16 + r16) * 64 + g4 * 8;
    int boff[3];
#pragma unroll
    for (int g = 0; g < 3; g++) boff[g] = (g * 64 + bcol) * 64 + g4 * 8;

    float pb[3];
#pragma unroll
    for (int g = 0; g < 3; g++) pb[g] = bp[tileW * 192 + g * 64 + bcol];

    const size_t aplane = (size_t)nMB * 8192;
    const _Float16* gA0 = X + (size_t)mb * 8192;
    const _Float16* gB0 = W + (size_t)tileW * 8 * 12288;

    half8 Ah[2][4], Al[2][4], Bh[2][3], Bl[2][3];
    auto LOADK = [&](int kt, int pp) {
        const _Float16* ga = gA0 + (size_t)kt * aplane;
        const _Float16* gb = gB0 + kt * 12288;
#pragma unroll
        for (int i = 0; i < 4; i++) {
            Ah[pp][i] = *(const half8*)&ga[aoff[i]];
            Al[pp][i] = *(const half8*)&ga[aoff[i] + 32];
        }
#pragma unroll
        for (int g = 0; g < 3; g++) {
            Bh[pp][g] = *(const half8*)&gb[boff[g]];
            Bl[pp][g] = *(const half8*)&gb[boff[g] + 32];
        }
    };

    f32x4 acc[4][3] = {};
    LOADK(0, 0);
#pragma unroll
    for (int kt = 0; kt < 8; kt++) {
        const int pp = kt & 1;
        if (kt < 7) LOADK(kt + 1, pp ^ 1);     // prefetch; counted vmcnt by compiler
        __builtin_amdgcn_s_setprio(1);
#pragma unroll
        for (int g = 0; g < 3; g++)
#pragma unroll
            for (int i = 0; i < 4; i++) {
                acc[i][g] = __builtin_amdgcn_mfma_f32_16x16x32_f16(Ah[pp][i], Bh[pp][g], acc[i][g], 0, 0, 0);
                acc[i][g] = __builtin_amdgcn_mfma_f32_16x16x32_f16(Ah[pp][i], Bl[pp][g], acc[i][g], 0, 0, 0);
                acc[i][g] = __builtin_amdgcn_mfma_f32_16x16x32_f16(Al[pp][i], Bh[pp][g], acc[i][g], 0, 0, 0);
            }
        __builtin_amdgcn_s_setprio(0);
    }

    if (OUTF32) {
        float* fb  = (float*)smh;               // [128][33]
        float* W2s = fb + 128 * 33;             // [10][32]
#pragma unroll
        for (int i = 0; i < 4; i++)
#pragma unroll
            for (int rr = 0; rr < 4; rr++) {
                int row = wr * 64 + i * 16 + g4 * 4 + rr;
                float gi = acc[i][0][rr] * inv + pb[0];
                float gg = acc[i][1][rr] * inv + pb[1];
                float go = acc[i][2][rr] * inv + pb[2];
                float c2 = sigm(gi) * tanh_(gg);
                fb[row * 33 + coll] = sigm(go) * tanh_(c2);
            }
        for (int idx = t; idx < 320; idx += 256)
            W2s[idx] = W2[(idx >> 5) * 256 + tile8 * 32 + (idx & 31)];
        __syncthreads();
        {
            int r = t & 127, jb = t >> 7;       // 5 outputs: j = jb + 2p
            float s[5] = {0, 0, 0, 0, 0};
            for (int c = 0; c < 32; c++) {
                float hv = fb[r * 33 + c];
#pragma unroll
                for (int p = 0; p < 5; p++) s[p] += hv * W2s[(jb + 2 * p) * 32 + c];
            }
            float* op = outP + (size_t)(m0 + r) * 80 + tile8 * 10;
#pragma unroll
            for (int p = 0; p < 5; p++) op[jb + 2 * p] = s[p];
        }
    } else {
        _Float16* sm = smh;                     // [128][64] linear stage
#pragma unroll
        for (int i = 0; i < 4; i++)
#pragma unroll
            for (int rr = 0; rr < 4; rr++) {
                int row = wr * 64 + i * 16 + g4 * 4 + rr;
                float gi = acc[i][0][rr] * inv + pb[0];
                float gg = acc[i][1][rr] * inv + pb[1];
                float go = acc[i][2][rr] * inv + pb[2];
                float c2 = sigm(gi) * tanh_(gg);
                float v  = 32.0f * sigm(go) * tanh_(c2);
                _Float16 hh = (_Float16)v;
                _Float16 ll = (_Float16)(v - (float)hh);
                sm[row * 64 + coll] = hh;
                sm[row * 64 + 32 + coll] = ll;
            }
        __syncthreads();
        _Float16* gH = H + (size_t)(tile8 * nMB + mb) * 8192;
#pragma unroll
        for (int c = 0; c < 4; c++)
            *(half8*)&gH[c * 2048 + t * 8] = *(const half8*)&smh[c * 2048 + t * 8];
    }
}

// ---------------------------------------------------------------------------
// Final: sum 8 tile-partials + b2, angles, Y-rotations. One thread per
// (sample, joint). outP is [CB][8][10].
// ---------------------------------------------------------------------------
__global__ __launch_bounds__(256) void final_kernel(
    const float* __restrict__ outP, const float* __restrict__ b2,
    const float* __restrict__ weight, const int* __restrict__ use_flag,
    const float* __restrict__ aM, const float* __restrict__ wM, const float* __restrict__ RMB,
    float* __restrict__ outA, float* __restrict__ outW, float* __restrict__ outR, int CB)
{
    int tid = blockIdx.x * 256 + threadIdx.x;
    if (tid >= CB * 6) return;
    int i = tid / 6, n = tid - i * 6;
    float c = 1.0f, s = 0.0f;
    if (n < 5) {
        const float* op = outP + (size_t)i * 80;
        float cr = b2[n], sr = b2[5 + n];
#pragma unroll
        for (int q = 0; q < 8; q++) { cr += op[q * 10 + n]; sr += op[q * 10 + 5 + n]; }
        float delta = (use_flag[0] != 0) ? (1.0f / 90.0f) : (-1.0f / 90.0f);
        float w = fminf(fmaxf(weight[i] + delta, 0.0f), 1.0f);
        float ang = atan2f(sr, cr) * w;
        float sa, ca;
        sincosf(ang, &sa, &ca);
        c = ca; s = -sa;
    }
    {
        const float* ap = aM + (size_t)i * 18 + n * 3;
        float* oa = outA + (size_t)i * 18 + n * 3;
        float a0 = ap[0], a1 = ap[1], a2 = ap[2];
        oa[0] = c * a0 + s * a2; oa[1] = a1; oa[2] = -s * a0 + c * a2;
    }
    {
        const float* wp = wM + (size_t)i * 18 + n * 3;
        float* ow = outW + (size_t)i * 18 + n * 3;
        float a0 = wp[0], a1 = wp[1], a2 = wp[2];
        ow[0] = c * a0 + s * a2; ow[1] = a1; ow[2] = -s * a0 + c * a2;
    }
    const float* rp = RMB + (size_t)i * 54 + n * 9;
    float* orp = outR + (size_t)i * 54 + n * 9;
#pragma unroll
    for (int k = 0; k < 3; k++) {
        float r0 = rp[k], r1 = rp[3 + k], r2 = rp[6 + k];
        orp[k] = c * r0 + s * r2; orp[3 + k] = r1; orp[6 + k] = -s * r0 + c * r2;
    }
}

// ---------------------------------------------------------------------------
extern "C" void kernel_launch(void* const* d_in, const int* in_sizes, int n_in,
                              void* d_out, int out_size, void* d_ws, size_t ws_size,
                              hipStream_t stream)
{
    const float* aM      = (const float*)d_in[0];
    const float* wM      = (const float*)d_in[1];
    const float* RMB     = (const float*)d_in[2];
    const float* weight  = (const float*)d_in[3];
    const float* W1      = (const float*)d_in[4];
    const float* b1      = (const float*)d_in[5];
    const float* Wih0    = (const float*)d_in[6];
    const float* bih0    = (const float*)d_in[8];
    const float* bhh0    = (const float*)d_in[9];
    const float* Wih1    = (const float*)d_in[10];
    const float* bih1    = (const float*)d_in[12];
    const float* bhh1    = (const float*)d_in[13];
    const float* W2      = (const float*)d_in[14];
    const float* b2      = (const float*)d_in[15];
    const int*   use_flag= (const int*)d_in[16];

    char* base = (char*)d_ws;
    size_t off = 0;
    auto alloc = [&](size_t n) { void* p = base + off; off = (off + n + 255) & ~(size_t)255; return p; };

    _Float16* W1sw  = (_Float16*)alloc(2 * 16384 * 2);
    _Float16* W0lin = (_Float16*)alloc(4 * 8 * 12288 * 2);
    _Float16* W1lin = (_Float16*)alloc(4 * 8 * 12288 * 2);
    float* bp0 = (float*)alloc(768 * 4);
    float* bp1 = (float*)alloc(768 * 4);
    size_t fixed = off;

    // per-sample: X 1024B + H1 1024B + outP 320B
    size_t perSample = 2368;
    int CB = BTOT;
    while (CB > 2048 && fixed + (size_t)CB * perSample + 65536 > ws_size) CB >>= 1;
    int nMB = CB / 128;

    _Float16* Xlin  = (_Float16*)alloc((size_t)CB * 1024);   // 512*CB halves
    _Float16* H1lin = (_Float16*)alloc((size_t)CB * 1024);
    float* outP     = (float*)alloc((size_t)CB * 320);

    pack_kernel<<<1600, 256, 0, stream>>>(W1, Wih0, bih0, bhh0, Wih1, bih1, bhh1,
                                          W1sw, W0lin, bp0, W1lin, bp1);

    float* outA = (float*)d_out;
    float* outW = outA + (size_t)BTOT * 18;
    float* outR = outW + (size_t)BTOT * 18;

    for (int b0 = 0; b0 < BTOT; b0 += CB) {
        gemm1_kernel<<<dim3(nMB, 2), 256, 0, stream>>>(
            aM + (size_t)b0 * 18, RMB + (size_t)b0 * 54, W1sw, b1, Xlin, nMB);
        lstm_kernel<0><<<nMB * 8, 256, 0, stream>>>(
            Xlin, W0lin, bp0, 1.0f / 256.0f, H1lin, nullptr, nullptr, nMB);
        lstm_kernel<1><<<nMB * 8, 256, 0, stream>>>(
            H1lin, W1lin, bp1, 1.0f / 1024.0f, nullptr, W2, outP, nMB);
        final_kernel<<<CB * 6 / 256, 256, 0, stream>>>(
            outP, b2, weight + b0, use_flag,
            aM + (size_t)b0 * 18, wM + (size_t)b0 * 18, RMB + (size_t)b0 * 54,
            outA + (size_t)b0 * 18, outW + (size_t)b0 * 18, outR + (size_t)b0 * 54, CB);
    }
}

// Round 9
// 205.379 us; speedup vs baseline: 1.5941x; 1.5941x over previous
//
#include <hip/hip_runtime.h>

#define BTOT 32768

using f32x4 = __attribute__((ext_vector_type(4))) float;
using half8 = __attribute__((ext_vector_type(8))) _Float16;

typedef const __attribute__((address_space(1))) unsigned int* gptr_t;
typedef __attribute__((address_space(3))) unsigned int* lptr_t;

__device__ __forceinline__ void gl2lds16(void* lds, const void* g) {
    __builtin_amdgcn_global_load_lds((gptr_t)g, (lptr_t)lds, 16, 0, 0);
}

__device__ __forceinline__ float sigm(float x) {
    return __builtin_amdgcn_rcpf(1.0f + __expf(-x));
}
__device__ __forceinline__ float tanh_(float x) {
    x = fminf(fmaxf(x, -15.0f), 15.0f);
    float e = __expf(2.0f * x);
    return (e - 1.0f) * __builtin_amdgcn_rcpf(e + 1.0f);
}

__device__ __forceinline__ float fatan2(float y, float x) {
    float ax = fabsf(x), ay = fabsf(y);
    float mx = fmaxf(ax, ay), mn = fminf(ax, ay);
    float a = mn * __builtin_amdgcn_rcpf(mx);
    float s = a * a;
    float r = a * (0.99997726f + s * (-0.33262347f + s * (0.19354346f +
              s * (-0.11643287f + s * (0.05265332f + s * -0.01172120f)))));
    if (ay > ax) r = 1.57079637f - r;
    if (x < 0.0f) r = 3.14159274f - r;
    return (y < 0.0f) ? -r : r;
}

// ---------------------------------------------------------------------------
// Swizzled layouts (R4): 128B rows of 8 x 16B granules, granule idx XOR (row&7).
//   W1sw: [2 nb][2 kt][128][64]     Wsw: [4 tile][8 kt][192][64]
//   Dsw:  [2 kt][nMB][128][64]      Xsw/H1sw: [8 kt][nMB][128][64]
// ---------------------------------------------------------------------------
__global__ __launch_bounds__(256) void pack_kernel(
    const float* __restrict__ W1,
    const float* __restrict__ Wih0, const float* __restrict__ bih0, const float* __restrict__ bhh0,
    const float* __restrict__ Wih1, const float* __restrict__ bih1, const float* __restrict__ bhh1,
    _Float16* __restrict__ W1sw,
    _Float16* __restrict__ W0sw, float* __restrict__ bp0,
    _Float16* __restrict__ W1sw_, float* __restrict__ bp1)
{
    int tid = blockIdx.x * 256 + threadIdx.x;
    if (tid < 256 * 64) {
        int n = tid >> 6, k = tid & 63;
        float v = (k < 63) ? 32.0f * W1[n * 63 + k] : 0.0f;
        _Float16 h = (_Float16)v;
        _Float16 l = (_Float16)(v - (float)h);
        int nb = n >> 7, r = n & 127, kt = k >> 5, kk = k & 31;
        size_t bb = (size_t)nb * 16384 + kt * 8192 + r * 64 + (kk & 7);
        W1sw[bb + ((((kk >> 3)) ^ (r & 7)) << 3)] = h;
        W1sw[bb + (((4 + (kk >> 3)) ^ (r & 7)) << 3)] = l;
    }
    int t2 = tid - 256 * 64;
    if (t2 >= 0 && t2 < 2 * 768 * 256) {
        int which = t2 / 196608;
        int rem   = t2 % 196608;
        int rlin = rem >> 8, k = rem & 255;
        int tile = rlin / 192;
        int rr = rlin - tile * 192;
        int g = rr >> 6, jj = rr & 63;
        int orig = ((g == 0) ? 0 : (g == 1) ? 512 : 768) + tile * 64 + jj;
        const float* W = which ? Wih1 : Wih0;
        float v = 32.0f * W[orig * 256 + k];
        _Float16 h = (_Float16)v;
        _Float16 l = (_Float16)(v - (float)h);
        int kt = k >> 5, kk = k & 31;
        _Float16* Wd = which ? W1sw_ : W0sw;
        size_t bb = (size_t)(tile * 8 + kt) * 12288 + rr * 64 + (kk & 7);
        Wd[bb + ((((kk >> 3)) ^ (rr & 7)) << 3)] = h;
        Wd[bb + (((4 + (kk >> 3)) ^ (rr & 7)) << 3)] = l;
        if (k == 0) {
            float bb2 = which ? (bih1[orig] + bhh1[orig]) : (bih0[orig] + bhh0[orig]);
            (which ? bp1 : bp0)[rlin] = bb2;
        }
    }
}

// ---------------------------------------------------------------------------
// Prep: per-sample 63 features -> split hi/lo fp16 -> swizzled Dsw image.
// Fully parallel (1 thread/sample).
// ---------------------------------------------------------------------------
__global__ __launch_bounds__(256) void prep_kernel(
    const float* __restrict__ aM, const float* __restrict__ RMB,
    _Float16* __restrict__ Dsw, int nMB, int CB)
{
    int i = blockIdx.x * 256 + threadIdx.x;
    if (i >= CB) return;
    const float* ap = aM + (size_t)i * 18;
    const float* rp = RMB + (size_t)i * 54;
    float a[18], R[54];
#pragma unroll
    for (int q = 0; q < 9; q++)  { float2 v = *(const float2*)&ap[q * 2]; a[q*2] = v.x; a[q*2+1] = v.y; }
#pragma unroll
    for (int q = 0; q < 27; q++) { float2 v = *(const float2*)&rp[q * 2]; R[q*2] = v.x; R[q*2+1] = v.y; }
    const float* R6 = R + 45;
    float d[64];
    d[0] = -10.0f * R6[3]; d[1] = -10.0f * R6[4]; d[2] = -10.0f * R6[5];
#pragma unroll
    for (int n = 0; n < 5; n++) {
        float v0 = a[n*3+0] - a[15], v1 = a[n*3+1] - a[16], v2 = a[n*3+2] - a[17];
#pragma unroll
        for (int k = 0; k < 3; k++)
            d[3 + n*3 + k] = v0 * R6[k] + v1 * R6[3 + k] + v2 * R6[6 + k];
    }
#pragma unroll
    for (int n = 0; n < 5; n++)
#pragma unroll
        for (int ii = 0; ii < 3; ii++)
#pragma unroll
            for (int k = 0; k < 3; k++)
                d[18 + n*9 + ii*3 + k] =
                    R6[ii] * R[n*9 + k] + R6[3 + ii] * R[n*9 + 3 + k] + R6[6 + ii] * R[n*9 + 6 + k];
    d[63] = 0.0f;
    int mb = i >> 7, r = i & 127, sx = r & 7;
#pragma unroll
    for (int kt = 0; kt < 2; kt++)
#pragma unroll
        for (int kg = 0; kg < 4; kg++) {
            _Float16 hh[8], ll[8];
#pragma unroll
            for (int e = 0; e < 8; e++) {
                int di = kt * 32 + kg * 8 + e;
                float v = (di < 63) ? 16.0f * d[di] : 0.0f;
                _Float16 h = (_Float16)v;
                hh[e] = h; ll[e] = (_Float16)(v - (float)h);
            }
            size_t base = ((size_t)kt * nMB + mb) * 8192 + (size_t)r * 64;
            *(half8*)&Dsw[base + ((kg ^ sx) << 3)]       = *(half8*)hh;
            *(half8*)&Dsw[base + (((kg + 4) ^ sx) << 3)] = *(half8*)ll;
        }
}

// ---------------------------------------------------------------------------
// GEMM1: x0 = relu(data @ W1^T + b1). BM=128, BN=128 (grid.y=2), K=64.
// A and B both staged via global_load_lds (swizzled images). All 256 threads
// on MFMA. Output X (scale 8) -> LDS restage -> coalesced half8 stores.
// ---------------------------------------------------------------------------
__global__ __launch_bounds__(256) void gemm1_kernel(
    const _Float16* __restrict__ Dsw, const _Float16* __restrict__ W1sw,
    const float* __restrict__ b1, _Float16* __restrict__ Xsw, int nMB)
{
    __shared__ _Float16 sm[32768];   // A:[2kt][128][64]=16384, B same
    const int t = threadIdx.x;
    const int mb = blockIdx.x, nb = blockIdx.y;
    {
        int o = t * 8;
#pragma unroll
        for (int kt2 = 0; kt2 < 2; kt2++)
#pragma unroll
            for (int q = 0; q < 4; q++)
                gl2lds16(&sm[kt2 * 8192 + q * 2048 + o],
                         &Dsw[((size_t)kt2 * nMB + mb) * 8192 + q * 2048 + o]);
#pragma unroll
        for (int it = 0; it < 8; it++)
            gl2lds16(&sm[16384 + o + it * 2048], &W1sw[(size_t)nb * 16384 + o + it * 2048]);
    }
    asm volatile("s_waitcnt vmcnt(0)" ::: "memory");
    __syncthreads();
    const int lane = t & 63, wid = t >> 6;
    const int wr = wid >> 1, wc = wid & 1;
    const int r16 = lane & 15, g4 = lane >> 4;
    const int sx = r16 & 7;
    const int aghi = (g4 ^ sx) << 3;
    const int aglo = ((g4 + 4) ^ sx) << 3;
    f32x4 acc[4][4] = {};
#pragma unroll
    for (int kt = 0; kt < 2; kt++) {
        half8 ah[4], al[4];
#pragma unroll
        for (int i = 0; i < 4; i++) {
            int ra = kt * 8192 + (wr * 64 + i * 16 + r16) * 64;
            ah[i] = *(const half8*)&sm[ra + aghi];
            al[i] = *(const half8*)&sm[ra + aglo];
        }
#pragma unroll
        for (int j = 0; j < 4; j++) {
            int rb = 16384 + kt * 8192 + (wc * 64 + j * 16 + r16) * 64;
            half8 bh = *(const half8*)&sm[rb + aghi];
            half8 bl = *(const half8*)&sm[rb + aglo];
#pragma unroll
            for (int i = 0; i < 4; i++) {
                acc[i][j] = __builtin_amdgcn_mfma_f32_16x16x32_f16(ah[i], bh, acc[i][j], 0, 0, 0);
                acc[i][j] = __builtin_amdgcn_mfma_f32_16x16x32_f16(ah[i], bl, acc[i][j], 0, 0, 0);
                acc[i][j] = __builtin_amdgcn_mfma_f32_16x16x32_f16(al[i], bh, acc[i][j], 0, 0, 0);
            }
        }
    }
    const float inv = 1.0f / 512.0f;
    __syncthreads();   // sm dead; reuse as output staging [4 kthL][128][64]
#pragma unroll
    for (int i = 0; i < 4; i++)
#pragma unroll
        for (int j = 0; j < 4; j++) {
            int col = nb * 128 + wc * 64 + j * 16 + r16;
            float bb = b1[col];
            int kthL = (col >> 5) & 3, kk = col & 31;
#pragma unroll
            for (int rr = 0; rr < 4; rr++) {
                int r = wr * 64 + i * 16 + g4 * 4 + rr;
                float v = fmaxf(acc[i][j][rr] * inv + bb, 0.0f) * 8.0f;
                _Float16 h = (_Float16)v;
                _Float16 l = (_Float16)(v - (float)h);
                int off = kthL * 8192 + r * 64 + (kk & 7);
                sm[off + ((((kk >> 3)) ^ (r & 7)) << 3)] = h;
                sm[off + (((4 + (kk >> 3)) ^ (r & 7)) << 3)] = l;
            }
        }
    __syncthreads();
#pragma unroll
    for (int c = 0; c < 16; c++)
        *(half8*)&Xsw[((size_t)(nb * 4 + (c >> 2)) * nMB + mb) * 8192 + (c & 3) * 2048 + t * 8] =
            *(half8*)&sm[c * 2048 + t * 8];
}

// ---------------------------------------------------------------------------
// LSTM GEMM — R4 structure verbatim (proven 51us): 2-phase dbuf, drain at
// iteration end, swizzled conflict-free LDS, fused activation. BM=128,
// BN=192, BK=32, 8 K-steps, 256 threads, 2 blocks/CU.
// ---------------------------------------------------------------------------
template<int OUTF32>
__global__ __launch_bounds__(256, 2) void lstm_kernel(
    const _Float16* __restrict__ Xsw, const _Float16* __restrict__ Wsw,
    const float* __restrict__ bp, float inv,
    _Float16* __restrict__ Hsw,
    const float* __restrict__ W2, float* __restrict__ outP, int nMB, int CB)
{
    extern __shared__ _Float16 lds[];   // 2 buffers x 20480 fp16 (40KB each)
    const int t = threadIdx.x;
    const int nwg = gridDim.x, hb = blockIdx.x;
    const int per = nwg >> 3;
    const int L = (hb & 7) * per + (hb >> 3);
    const int mb = L >> 2, tile = L & 3;
    const int m0 = mb * 128, n0 = tile * 192;

    auto STAGE = [&](int kt, int buf) {
        _Float16* base = lds + buf * 20480;
        const _Float16* gA = Xsw + ((size_t)kt * nMB + mb) * 8192;
        const _Float16* gB = Wsw + (size_t)(tile * 8 + kt) * 12288;
        int o = t * 8;
#pragma unroll
        for (int it = 0; it < 4; it++)
            gl2lds16(&base[o + it * 2048], &gA[o + it * 2048]);
#pragma unroll
        for (int it = 0; it < 6; it++)
            gl2lds16(&base[8192 + o + it * 2048], &gB[o + it * 2048]);
    };

    const int lane = t & 63, wid = t >> 6;
    const int wr = wid >> 1, wc = wid & 1;
    const int r16 = lane & 15, g4 = lane >> 4;
    const int sx = r16 & 7;
    const int aghi = (g4 ^ sx) << 3;
    const int aglo = ((g4 + 4) ^ sx) << 3;
    f32x4 acc[4][6] = {};

    STAGE(0, 0);
    asm volatile("s_waitcnt vmcnt(0)" ::: "memory");
    __builtin_amdgcn_s_barrier();
    __builtin_amdgcn_sched_barrier(0);
#pragma unroll
    for (int kt = 0; kt < 8; kt++) {
        const int cur = kt & 1;
        if (kt < 7) STAGE(kt + 1, cur ^ 1);
        const _Float16* B = lds + cur * 20480;
        half8 ah[4], al[4];
#pragma unroll
        for (int i = 0; i < 4; i++) {
            int ra = (wr * 64 + i * 16 + r16) * 64;
            ah[i] = *(const half8*)&B[ra + aghi];
            al[i] = *(const half8*)&B[ra + aglo];
        }
        __builtin_amdgcn_s_setprio(1);
#pragma unroll
        for (int j = 0; j < 6; j++) {
            int rb = 8192 + ((j >> 1) * 64 + wc * 32 + (j & 1) * 16 + r16) * 64;
            half8 bh = *(const half8*)&B[rb + aghi];
            half8 bl = *(const half8*)&B[rb + aglo];
#pragma unroll
            for (int i = 0; i < 4; i++) {
                acc[i][j] = __builtin_amdgcn_mfma_f32_16x16x32_f16(ah[i], bh, acc[i][j], 0, 0, 0);
                acc[i][j] = __builtin_amdgcn_mfma_f32_16x16x32_f16(ah[i], bl, acc[i][j], 0, 0, 0);
                acc[i][j] = __builtin_amdgcn_mfma_f32_16x16x32_f16(al[i], bh, acc[i][j], 0, 0, 0);
            }
        }
        __builtin_amdgcn_s_setprio(0);
        if (kt < 7) {
            asm volatile("s_waitcnt vmcnt(0)" ::: "memory");
            __builtin_amdgcn_s_barrier();
            __builtin_amdgcn_sched_barrier(0);
        }
    }

    if (OUTF32) {
        float* fb  = (float*)lds;              // [128][65] in buf0 (dead)
        float* W2s = fb + 128 * 65;            // [10][64]
#pragma unroll
        for (int i = 0; i < 4; i++)
#pragma unroll
            for (int u = 0; u < 2; u++) {
                int coll = wc * 32 + u * 16 + r16;
                float bi = bp[n0 + coll];
                float bg = bp[n0 + 64 + coll];
                float bo = bp[n0 + 128 + coll];
#pragma unroll
                for (int rr = 0; rr < 4; rr++) {
                    int rowl = wr * 64 + i * 16 + g4 * 4 + rr;
                    float gi = acc[i][0 + u][rr] * inv + bi;
                    float gg = acc[i][2 + u][rr] * inv + bg;
                    float go = acc[i][4 + u][rr] * inv + bo;
                    float c2 = sigm(gi) * tanh_(gg);
                    fb[rowl * 65 + coll] = sigm(go) * tanh_(c2);
                }
            }
        for (int idx = t; idx < 640; idx += 256)
            W2s[idx] = W2[(idx >> 6) * 256 + tile * 64 + (idx & 63)];
        __syncthreads();
        {
            int r = t & 127, jb = t >> 7;      // 5 outputs: j = jb + 2p
            float s[5] = {0, 0, 0, 0, 0};
            for (int c = 0; c < 64; c++) {
                float hv = fb[r * 65 + c];
#pragma unroll
                for (int p = 0; p < 5; p++) s[p] += hv * W2s[(jb + 2 * p) * 64 + c];
            }
            float* op = outP + (size_t)(m0 + r) * 40 + tile * 10;
#pragma unroll
            for (int p = 0; p < 5; p++) op[jb + 2 * p] = s[p];
        }
    } else {
#pragma unroll
        for (int i = 0; i < 4; i++)
#pragma unroll
            for (int u = 0; u < 2; u++) {
                int coll = wc * 32 + u * 16 + r16;
                int colg = tile * 64 + coll;
                float bi = bp[n0 + coll];
                float bg = bp[n0 + 64 + coll];
                float bo = bp[n0 + 128 + coll];
                int kth = colg >> 5, kk = colg & 31;
#pragma unroll
                for (int rr = 0; rr < 4; rr++) {
                    int r = wr * 64 + i * 16 + g4 * 4 + rr;
                    float gi = acc[i][0 + u][rr] * inv + bi;
                    float gg = acc[i][2 + u][rr] * inv + bg;
                    float go = acc[i][4 + u][rr] * inv + bo;
                    float c2 = sigm(gi) * tanh_(gg);
                    float v  = 32.0f * sigm(go) * tanh_(c2);
                    _Float16 hh = (_Float16)v;
                    _Float16 ll = (_Float16)(v - (float)hh);
                    size_t bbq = ((size_t)kth * nMB + mb) * 8192 + r * 64 + (kk & 7);
                    int gh = (kk >> 3) ^ (r & 7);
                    int gl = (4 + (kk >> 3)) ^ (r & 7);
                    Hsw[bbq + (gh << 3)] = hh;
                    Hsw[bbq + (gl << 3)] = ll;
                }
            }
    }
}

// ---------------------------------------------------------------------------
// Final: sum 4 tile-partials + b2, fast atan2/sincos, Y-rotations.
// One thread per (sample, joint). outP is [CB][4][10].
// ---------------------------------------------------------------------------
__global__ __launch_bounds__(256) void final_kernel(
    const float* __restrict__ outP, const float* __restrict__ b2,
    const float* __restrict__ weight, const int* __restrict__ use_flag,
    const float* __restrict__ aM, const float* __restrict__ wM, const float* __restrict__ RMB,
    float* __restrict__ outA, float* __restrict__ outW, float* __restrict__ outR, int CB)
{
    int tid = blockIdx.x * 256 + threadIdx.x;
    if (tid >= CB * 6) return;
    int i = tid / 6, n = tid - i * 6;
    float c = 1.0f, s = 0.0f;
    if (n < 5) {
        const float* op = outP + (size_t)i * 40;
        float cr = b2[n]     + op[n]     + op[10 + n] + op[20 + n] + op[30 + n];
        float sr = b2[5 + n] + op[5 + n] + op[15 + n] + op[25 + n] + op[35 + n];
        float delta = (use_flag[0] != 0) ? (1.0f / 90.0f) : (-1.0f / 90.0f);
        float w = fminf(fmaxf(weight[i] + delta, 0.0f), 1.0f);
        float ang = fatan2(sr, cr) * w;
        float sa = __sinf(ang), ca = __cosf(ang);
        c = ca; s = -sa;
    }
    {
        const float* ap = aM + (size_t)i * 18 + n * 3;
        float* oa = outA + (size_t)i * 18 + n * 3;
        float a0 = ap[0], a1 = ap[1], a2 = ap[2];
        oa[0] = c * a0 + s * a2; oa[1] = a1; oa[2] = -s * a0 + c * a2;
    }
    {
        const float* wp = wM + (size_t)i * 18 + n * 3;
        float* ow = outW + (size_t)i * 18 + n * 3;
        float a0 = wp[0], a1 = wp[1], a2 = wp[2];
        ow[0] = c * a0 + s * a2; ow[1] = a1; ow[2] = -s * a0 + c * a2;
    }
    const float* rp = RMB + (size_t)i * 54 + n * 9;
    float* orp = outR + (size_t)i * 54 + n * 9;
#pragma unroll
    for (int k = 0; k < 3; k++) {
        float r0 = rp[k], r1 = rp[3 + k], r2 = rp[6 + k];
        orp[k] = c * r0 + s * r2; orp[3 + k] = r1; orp[6 + k] = -s * r0 + c * r2;
    }
}

// ---------------------------------------------------------------------------
extern "C" void kernel_launch(void* const* d_in, const int* in_sizes, int n_in,
                              void* d_out, int out_size, void* d_ws, size_t ws_size,
                              hipStream_t stream)
{
    const float* aM      = (const float*)d_in[0];
    const float* wM      = (const float*)d_in[1];
    const float* RMB     = (const float*)d_in[2];
    const float* weight  = (const float*)d_in[3];
    const float* W1      = (const float*)d_in[4];
    const float* b1      = (const float*)d_in[5];
    const float* Wih0    = (const float*)d_in[6];
    const float* bih0    = (const float*)d_in[8];
    const float* bhh0    = (const float*)d_in[9];
    const float* Wih1    = (const float*)d_in[10];
    const float* bih1    = (const float*)d_in[12];
    const float* bhh1    = (const float*)d_in[13];
    const float* W2      = (const float*)d_in[14];
    const float* b2      = (const float*)d_in[15];
    const int*   use_flag= (const int*)d_in[16];

    char* base = (char*)d_ws;
    size_t off = 0;
    auto alloc = [&](size_t n) { void* p = base + off; off = (off + n + 255) & ~(size_t)255; return p; };

    _Float16* W1sw = (_Float16*)alloc(2 * 16384 * 2);
    _Float16* W0sw = (_Float16*)alloc(4 * 8 * 12288 * 2);
    _Float16* Wssw = (_Float16*)alloc(4 * 8 * 12288 * 2);
    float* bp0 = (float*)alloc(768 * 4);
    float* bp1 = (float*)alloc(768 * 4);
    size_t fixed = off;

    // per-sample: D 256B + X 1024B + H1 1024B + outP 160B
    size_t perSample = 2464;
    int CB = BTOT;
    while (CB > 2048 && fixed + (size_t)CB * perSample + 65536 > ws_size) CB >>= 1;
    int nMB = CB / 128;

    _Float16* Dsw  = (_Float16*)alloc((size_t)CB * 256);    // 128*CB halves
    _Float16* Xsw  = (_Float16*)alloc((size_t)CB * 1024);   // 512*CB halves
    _Float16* H1sw = (_Float16*)alloc((size_t)CB * 1024);
    float* outP    = (float*)alloc((size_t)CB * 160);

    hipFuncSetAttribute((const void*)lstm_kernel<0>,
                        hipFuncAttributeMaxDynamicSharedMemorySize, 81920);
    hipFuncSetAttribute((const void*)lstm_kernel<1>,
                        hipFuncAttributeMaxDynamicSharedMemorySize, 81920);

    pack_kernel<<<1600, 256, 0, stream>>>(W1, Wih0, bih0, bhh0, Wih1, bih1, bhh1,
                                          W1sw, W0sw, bp0, Wssw, bp1);

    float* outA = (float*)d_out;
    float* outW = outA + (size_t)BTOT * 18;
    float* outR = outW + (size_t)BTOT * 18;

    for (int b0 = 0; b0 < BTOT; b0 += CB) {
        prep_kernel<<<CB / 256, 256, 0, stream>>>(
            aM + (size_t)b0 * 18, RMB + (size_t)b0 * 54, Dsw, nMB, CB);
        gemm1_kernel<<<dim3(nMB, 2), 256, 0, stream>>>(
            Dsw, W1sw, b1, Xsw, nMB);
        lstm_kernel<0><<<nMB * 4, 256, 81920, stream>>>(
            Xsw, W0sw, bp0, 1.0f / 256.0f, H1sw, nullptr, nullptr, nMB, CB);
        lstm_kernel<1><<<nMB * 4, 256, 81920, stream>>>(
            H1sw, Wssw, bp1, 1.0f / 1024.0f, nullptr, W2, outP, nMB, CB);
        final_kernel<<<CB * 6 / 256, 256, 0, stream>>>(
            outP, b2, weight + b0, use_flag,
            aM + (size_t)b0 * 18, wM + (size_t)b0 * 18, RMB + (size_t)b0 * 54,
            outA + (size_t)b0 * 18, outW + (size_t)b0 * 18, outR + (size_t)b0 * 54, CB);
    }
}